// Round 2
// baseline (683.831 us; speedup 1.0000x reference)
//
#include <hip/hip_runtime.h>
#include <cstddef>

// Problem constants
#define NPTS   65536
#define BATCH  4
#define CH     256
#define HWBINS 64     // 8 x 8
#define KDIM   16384  // HWBINS * CH
#define JDIM   512
#define SSLOTS 8      // slot-spread copies of sums (atomic contention killer)
#define GSLOTS 64     // slot-spread copies of gemm partials
#define ZERO_F4 ((SSLOTS * BATCH * KDIM + GSLOTS * 2048) / 4)   // 163840 float4 = 2.5 MB

// k_seg geometry: sequential stream + LDS bin-accumulate (no sort).
#define SEGGRID 256                                  // 1 block/CU
#define SEGTHR  512                                  // 8 waves/block
#define CHUNKS_PER_B   (SEGGRID / BATCH)             // 64 row-chunks per batch
#define ROWS_PER_CHUNK (NPTS / CHUNKS_PER_B)         // 1024 rows per block
#define ROWS_PER_WAVE  (ROWS_PER_CHUNK / (SEGTHR/64))// 128 rows per wave

// Native clang vector types — __builtin_nontemporal_load requires these.
typedef float vf2 __attribute__((ext_vector_type(2)));

__device__ __forceinline__ float ntload1(const float* p) {
    return __builtin_nontemporal_load(p);
}
__device__ __forceinline__ float2 ntload2(const float* p) {
    vf2 v = __builtin_nontemporal_load((const vf2*)p);
    return make_float2(v.x, v.y);
}

// ---------------------------------------------------------------------------
// Bucketization matching np.searchsorted(np.linspace(-1-eps, 1+eps, 9), x,
// 'right'). np.linspace is float64. (Verified: absmax 6e-5.)
// ---------------------------------------------------------------------------
__device__ __forceinline__ int bucket1d(float xf) {
    const double start = -1.0 - 1e-6;
    const double stop  =  1.0 + 1e-6;
    const double step  = (stop - start) / 8.0;
    double x = (double)xf;
    int k = 0;
#pragma unroll
    for (int i = 0; i < 8; ++i) k += ((double)i * step + start <= x) ? 1 : 0;
    k += (stop <= x) ? 1 : 0;
    int b = k - 1;
    return b < 0 ? 0 : (b > 7 ? 7 : b);
}

// Kernel 1: zero sums8+out_part (contiguous 2.5 MB) + per-point bin +
// per-block histogram. 64 blocks x 256 threads.
__global__ __launch_bounds__(256) void k_bins(const float* __restrict__ coords,
                                              int* __restrict__ bins,
                                              int* __restrict__ hist_blk,
                                              float4* __restrict__ zero4) {
    __shared__ int s_h[HWBINS];
    const int tid = threadIdx.x;
    const int blk = blockIdx.x;
    {
        const float4 z = make_float4(0.f, 0.f, 0.f, 0.f);
        for (int i = blk * 256 + tid; i < ZERO_F4; i += 64 * 256)
            zero4[i] = z;
    }
    if (tid < HWBINS) s_h[tid] = 0;
    __syncthreads();
#pragma unroll
    for (int i = 0; i < 4; ++i) {
        int n = blk * 1024 + i * 256 + tid;
        float2 xy = *(const float2*)(coords + 2 * (size_t)n);
        int bx = bucket1d(xy.x);
        int by = bucket1d(xy.y);
        int bin = by * 8 + bx;   // (kx-1) + (ky-1)*H, H=8
        bins[n] = bin;
        atomicAdd(&s_h[bin], 1);
    }
    __syncthreads();
    if (tid < HWBINS) hist_blk[blk * HWBINS + tid] = s_h[tid];
}

// Kernel 2: one wave. counts[bin] only.
__global__ void k_counts(const int* __restrict__ hist_blk,
                         int* __restrict__ counts) {
    const int b = threadIdx.x;   // 0..63
    int tot = 0;
#pragma unroll 8
    for (int blk = 0; blk < 64; ++blk) tot += hist_blk[blk * HWBINS + b];
    counts[b] = tot;
}

// ---------------------------------------------------------------------------
// Kernel 3: the 256 MB pass — pure sequential stream. 256 blocks (1/CU,
// 8 waves), block = (batch, 1024-row chunk). LDS accumulator
// s_acc[64 bins][256 ch] = 64 KB. R1 post-mortem: plain atomicAdd(float*)
// on LDS lowered to a CAS loop (~200 cyc/op -> 340 us, VALUBusy 0.2%).
// Fix: unsafeAtomicAdd -> native no-return ds_add_f32 (~5 cyc).
// Lane owns ch {L, 64+L, 128+L, 192+L}: ds bank = lane%32 -> 2 lanes/bank
// = conflict-free (m136: 2-way is free). LDS pipe ~8.5 us << 43 us stream.
// 8-deep prefetch of 4 NT dword loads/row (256 B coalesced each):
// 8 KB/lane-group in flight per wave, 64 KB/CU vs ~9 KB needed at 6.3 TB/s.
// Flush: coalesced unsafeAtomicAdd into 8-slot global sums (R0's proven
// pattern) — no partials round-trip.
// ---------------------------------------------------------------------------
__global__ __launch_bounds__(SEGTHR) void k_seg(const float* __restrict__ values,
                                                const int* __restrict__ bins,
                                                float* __restrict__ sums8) {
    __shared__ float s_acc[KDIM];             // 64 KB
    __shared__ int   s_bin[ROWS_PER_CHUNK];   // 4 KB
    const int tid   = threadIdx.x;
    const int b     = blockIdx.x >> 6;        // batch
    const int chunk = blockIdx.x & 63;
    const int r0    = chunk * ROWS_PER_CHUNK;
    {
        float4* s4 = (float4*)s_acc;
        const float4 z = make_float4(0.f, 0.f, 0.f, 0.f);
#pragma unroll
        for (int i = tid; i < KDIM / 4; i += SEGTHR) s4[i] = z;
#pragma unroll
        for (int i = tid; i < ROWS_PER_CHUNK; i += SEGTHR) s_bin[i] = bins[r0 + i];
    }
    __syncthreads();

    const int wid  = tid >> 6;
    const int lane = tid & 63;
    const int lr0  = wid * ROWS_PER_WAVE;               // local row base
    const float* vb = values + ((size_t)b * NPTS + r0 + lr0) * CH + lane;

    float a0[8], a1[8], a2[8], a3[8];
    float n0[8], n1[8], n2[8], n3[8];
    int   ab[8], nb[8];
#pragma unroll
    for (int j = 0; j < 8; ++j) {
        const float* p = vb + (size_t)j * CH;
        a0[j] = ntload1(p);       a1[j] = ntload1(p + 64);
        a2[j] = ntload1(p + 128); a3[j] = ntload1(p + 192);
        ab[j] = s_bin[lr0 + j];
    }
#pragma unroll
    for (int g = 0; g < ROWS_PER_WAVE; g += 8) {
        if (g + 8 < ROWS_PER_WAVE) {    // issue next group's loads first
#pragma unroll
            for (int j = 0; j < 8; ++j) {
                const float* p = vb + (size_t)(g + 8 + j) * CH;
                n0[j] = ntload1(p);       n1[j] = ntload1(p + 64);
                n2[j] = ntload1(p + 128); n3[j] = ntload1(p + 192);
                nb[j] = s_bin[lr0 + g + 8 + j];
            }
        }
#pragma unroll
        for (int j = 0; j < 8; ++j) {
            float* d = s_acc + ab[j] * CH + lane;
            unsafeAtomicAdd(d + 0,   a0[j]);   // ds_add_f32, no return
            unsafeAtomicAdd(d + 64,  a1[j]);
            unsafeAtomicAdd(d + 128, a2[j]);
            unsafeAtomicAdd(d + 192, a3[j]);
        }
        if (g + 8 < ROWS_PER_WAVE) {
#pragma unroll
            for (int j = 0; j < 8; ++j) {
                a0[j] = n0[j]; a1[j] = n1[j]; a2[j] = n2[j]; a3[j] = n3[j];
                ab[j] = nb[j];
            }
        }
    }
    __syncthreads();
    {   // flush: 16K floats, coalesced, 8-way slot spread kills contention
        const int slot = chunk & (SSLOTS - 1);
        float* sb = sums8 + ((size_t)slot * BATCH + b) * KDIM;
#pragma unroll
        for (int i = tid; i < KDIM; i += SEGTHR)
            unsafeAtomicAdd(sb + i, s_acc[i]);
    }
}

// ---------------------------------------------------------------------------
// Kernel 4: GEMM partials (unchanged proven kernel). 512 blocks (k-chunks
// of 32, 2/CU), 256 thr, each thread owns a float2 of j for all 4 batches.
// Means (8-slot sum / count) computed into LDS. 32 fully-unrolled
// nontemporal W loads in flight. Partials into 64 slots.
// ---------------------------------------------------------------------------
__global__ __launch_bounds__(256) void k_gemm_a(const float* __restrict__ Wm,
                                                const float* __restrict__ sums8,
                                                const int* __restrict__ counts,
                                                float* __restrict__ out_part) {
    __shared__ float s_m[4 * 32];   // [batch][kk]
    const int tid = threadIdx.x;
    const int kc  = blockIdx.x;     // 0..511
    const int k0  = kc * 32;
    if (tid < 128) {
        int bb = tid >> 5, kk = tid & 31, k = k0 + kk;
        float s = 0.f;
#pragma unroll
        for (int sl = 0; sl < SSLOTS; ++sl)
            s += sums8[(size_t)sl * BATCH * KDIM + (size_t)bb * KDIM + k];
        float cnt = (float)counts[k >> 8];
        s_m[tid] = s / fmaxf(cnt, 1.0f);
    }
    __syncthreads();

    const float* wp = Wm + (size_t)k0 * JDIM + 2 * tid;
    float2 a0 = {0.f, 0.f}, a1 = {0.f, 0.f}, a2 = {0.f, 0.f}, a3 = {0.f, 0.f};
#pragma unroll
    for (int kk = 0; kk < 32; ++kk) {
        float2 w = ntload2(wp + (size_t)kk * JDIM);
        float m0 = s_m[kk], m1 = s_m[32 + kk], m2 = s_m[64 + kk], m3 = s_m[96 + kk];
        a0.x += m0 * w.x; a0.y += m0 * w.y;
        a1.x += m1 * w.x; a1.y += m1 * w.y;
        a2.x += m2 * w.x; a2.y += m2 * w.y;
        a3.x += m3 * w.x; a3.y += m3 * w.y;
    }
    const int slot = kc & (GSLOTS - 1);
    float* op = out_part + (size_t)slot * 2048 + 2 * tid;
    unsafeAtomicAdd(op + 0,    a0.x); unsafeAtomicAdd(op + 1,    a0.y);
    unsafeAtomicAdd(op + 512,  a1.x); unsafeAtomicAdd(op + 513,  a1.y);
    unsafeAtomicAdd(op + 1024, a2.x); unsafeAtomicAdd(op + 1025, a2.y);
    unsafeAtomicAdd(op + 1536, a3.x); unsafeAtomicAdd(op + 1537, a3.y);
}

// Kernel 5: reduce 64 slots + bias -> out[4][512]. 512 KB read by 8 blocks.
__global__ __launch_bounds__(256) void k_gemm_b(const float* __restrict__ out_part,
                                                const float* __restrict__ bias,
                                                float* __restrict__ out) {
    const int idx = blockIdx.x * 256 + threadIdx.x;   // 0..2047
    const int j = idx & 511;
    float s = bias[j];
#pragma unroll
    for (int sl = 0; sl < GSLOTS; ++sl) s += out_part[(size_t)sl * 2048 + idx];
    out[idx] = s;
}

// ---------------------------------------------------------------------------
extern "C" void kernel_launch(void* const* d_in, const int* in_sizes, int n_in,
                              void* d_out, int out_size, void* d_ws, size_t ws_size,
                              hipStream_t stream) {
    const float* values = (const float*)d_in[0];  // [4, 65536, 256]
    const float* coords = (const float*)d_in[1];  // [65536, 2]
    const float* Wm     = (const float*)d_in[2];  // [16384, 512]
    const float* bias   = (const float*)d_in[3];  // [512]
    float* out = (float*)d_out;                   // [4, 512]

    char* ws = (char*)d_ws;
    // ws layout (bytes):
    int*   bins     = (int*)(ws + 0);            //  256 KB
    int*   hist_blk = (int*)(ws + 262144);       //   16 KB
    int*   counts   = (int*)(ws + 278528);       //  256 B
    float* sums8    = (float*)(ws + 278784);     //    2 MB  [8][4][16384]
    float* out_part = (float*)(ws + 2375936);    //  512 KB  [64][2048] (MUST follow sums8: zeroed as one range)

    k_bins  <<<64, 256, 0, stream>>>(coords, bins, hist_blk, (float4*)sums8);
    k_counts<<<1, 64, 0, stream>>>(hist_blk, counts);
    k_seg   <<<SEGGRID, SEGTHR, 0, stream>>>(values, bins, sums8);
    k_gemm_a<<<512, 256, 0, stream>>>(Wm, sums8, counts, out_part);
    k_gemm_b<<<8, 256, 0, stream>>>(out_part, bias, out);
}

// Round 3
// 681.826 us; speedup vs baseline: 1.0029x; 1.0029x over previous
//
#include <hip/hip_runtime.h>
#include <cstddef>

// Problem constants
#define NPTS   65536
#define BATCH  4
#define CH     256
#define HWBINS 64     // 8 x 8
#define KDIM   16384  // HWBINS * CH
#define JDIM   512
#define SSLOTS 8      // slot-spread copies of sums (atomic contention killer)
#define GSLOTS 64     // slot-spread copies of gemm partials
#define ZERO_F4 ((SSLOTS * BATCH * KDIM + GSLOTS * 2048) / 4)   // 163840 float4 = 2.5 MB

// k_seg geometry: sequential stream + LDS bin-accumulate (no sort).
#define SEGGRID 256                                  // 1 block/CU
#define SEGTHR  512                                  // 8 waves/block
#define CHUNKS_PER_B   (SEGGRID / BATCH)             // 64 row-chunks per batch
#define ROWS_PER_CHUNK (NPTS / CHUNKS_PER_B)         // 1024 rows per block
#define ROWS_PER_WAVE  (ROWS_PER_CHUNK / (SEGTHR/64))// 128 rows per wave

// Native clang vector types — __builtin_nontemporal_load requires these.
typedef float vf4 __attribute__((ext_vector_type(4)));
typedef float vf2 __attribute__((ext_vector_type(2)));

__device__ __forceinline__ float4 ntload4(const float* p) {
    vf4 v = __builtin_nontemporal_load((const vf4*)p);
    return make_float4(v.x, v.y, v.z, v.w);
}
__device__ __forceinline__ float2 ntload2(const float* p) {
    vf2 v = __builtin_nontemporal_load((const vf2*)p);
    return make_float2(v.x, v.y);
}

// ---------------------------------------------------------------------------
// Bucketization matching np.searchsorted(np.linspace(-1-eps, 1+eps, 9), x,
// 'right'). np.linspace is float64. (Verified: absmax 6e-5.)
// ---------------------------------------------------------------------------
__device__ __forceinline__ int bucket1d(float xf) {
    const double start = -1.0 - 1e-6;
    const double stop  =  1.0 + 1e-6;
    const double step  = (stop - start) / 8.0;
    double x = (double)xf;
    int k = 0;
#pragma unroll
    for (int i = 0; i < 8; ++i) k += ((double)i * step + start <= x) ? 1 : 0;
    k += (stop <= x) ? 1 : 0;
    int b = k - 1;
    return b < 0 ? 0 : (b > 7 ? 7 : b);
}

// Kernel 1: zero sums8+out_part (contiguous 2.5 MB) + per-point bin +
// per-block histogram. 64 blocks x 256 threads.
__global__ __launch_bounds__(256) void k_bins(const float* __restrict__ coords,
                                              int* __restrict__ bins,
                                              int* __restrict__ hist_blk,
                                              float4* __restrict__ zero4) {
    __shared__ int s_h[HWBINS];
    const int tid = threadIdx.x;
    const int blk = blockIdx.x;
    {
        const float4 z = make_float4(0.f, 0.f, 0.f, 0.f);
        for (int i = blk * 256 + tid; i < ZERO_F4; i += 64 * 256)
            zero4[i] = z;
    }
    if (tid < HWBINS) s_h[tid] = 0;
    __syncthreads();
#pragma unroll
    for (int i = 0; i < 4; ++i) {
        int n = blk * 1024 + i * 256 + tid;
        float2 xy = *(const float2*)(coords + 2 * (size_t)n);
        int bx = bucket1d(xy.x);
        int by = bucket1d(xy.y);
        int bin = by * 8 + bx;   // (kx-1) + (ky-1)*H, H=8
        bins[n] = bin;
        atomicAdd(&s_h[bin], 1);
    }
    __syncthreads();
    if (tid < HWBINS) hist_blk[blk * HWBINS + tid] = s_h[tid];
}

// Kernel 2: one wave. counts[bin] only.
__global__ void k_counts(const int* __restrict__ hist_blk,
                         int* __restrict__ counts) {
    const int b = threadIdx.x;   // 0..63
    int tot = 0;
#pragma unroll 8
    for (int blk = 0; blk < 64; ++blk) tot += hist_blk[blk * HWBINS + b];
    counts[b] = tot;
}

// ---------------------------------------------------------------------------
// Kernel 3: the 256 MB pass — pure sequential stream. 256 blocks (1/CU,
// 8 waves), block = (batch, 1024-row chunk). LDS accumulator
// s_acc[64 bins][256 ch] = 64 KB.
// R2 post-mortem: VGPR_Count=52 -> compiler could not keep the prefetch
// arrays in registers (launch_bounds(512) defaulted to a high-occupancy
// reg budget), so every load was rematerialized next to its ds_add ->
// zero MLP, 512 serial ~1600cyc load-use chains/wave = 346 us. Fix:
// (a) __launch_bounds__(512, 2): we run exactly 1 block/CU (68 KB LDS)
//     = 2 waves/EU -> unlock ~512 VGPR/wave budget;
// (b) float4 loads (R0's proven shape): lane = 16B channel-group, one
//     global_load_dwordx4 per ROW per wave (128 loads/wave, 8-deep
//     row prefetch = 8 KB/lane-group in flight, 64 KB/CU vs 9 KB needed).
// ds side: all lanes same bin (row is wave-uniform), addr stride 4 dwords
// -> 8-way bank alias ~2.9x (m136) = ~24cyc/row, ~10us/CU LDS pipe,
// hidden under the ~41 us memory stream.
// Flush: coalesced unsafeAtomicAdd into 8-slot global sums (proven).
// ---------------------------------------------------------------------------
__global__ __launch_bounds__(SEGTHR, 2) void k_seg(const float* __restrict__ values,
                                                   const int* __restrict__ bins,
                                                   float* __restrict__ sums8) {
    __shared__ float s_acc[KDIM];             // 64 KB
    __shared__ int   s_bin[ROWS_PER_CHUNK];   // 4 KB
    const int tid   = threadIdx.x;
    const int b     = blockIdx.x >> 6;        // batch
    const int chunk = blockIdx.x & 63;
    const int r0    = chunk * ROWS_PER_CHUNK;
    {
        float4* s4 = (float4*)s_acc;
        const float4 z = make_float4(0.f, 0.f, 0.f, 0.f);
#pragma unroll
        for (int i = tid; i < KDIM / 4; i += SEGTHR) s4[i] = z;
#pragma unroll
        for (int i = tid; i < ROWS_PER_CHUNK; i += SEGTHR) s_bin[i] = bins[r0 + i];
    }
    __syncthreads();

    const int wid  = tid >> 6;
    const int lane = tid & 63;
    const int lr0  = wid * ROWS_PER_WAVE;               // local row base
    // lane-th float4 of each row; row stride = CH floats
    const float* vb = values + ((size_t)b * NPTS + r0 + lr0) * CH + lane * 4;

    float4 a[8], n[8];
    int    ab[8], nb[8];
#pragma unroll
    for (int j = 0; j < 8; ++j) {
        a[j]  = ntload4(vb + (size_t)j * CH);
        ab[j] = s_bin[lr0 + j];
    }
#pragma unroll
    for (int g = 0; g < ROWS_PER_WAVE; g += 8) {
        if (g + 8 < ROWS_PER_WAVE) {    // issue next group's loads first
#pragma unroll
            for (int j = 0; j < 8; ++j) {
                n[j]  = ntload4(vb + (size_t)(g + 8 + j) * CH);
                nb[j] = s_bin[lr0 + g + 8 + j];
            }
        }
#pragma unroll
        for (int j = 0; j < 8; ++j) {
            float* d = s_acc + ab[j] * CH + lane * 4;
            unsafeAtomicAdd(d + 0, a[j].x);   // ds_add_f32, no return
            unsafeAtomicAdd(d + 1, a[j].y);
            unsafeAtomicAdd(d + 2, a[j].z);
            unsafeAtomicAdd(d + 3, a[j].w);
        }
        if (g + 8 < ROWS_PER_WAVE) {
#pragma unroll
            for (int j = 0; j < 8; ++j) { a[j] = n[j]; ab[j] = nb[j]; }
        }
    }
    __syncthreads();
    {   // flush: 16K floats, coalesced, 8-way slot spread kills contention
        const int slot = chunk & (SSLOTS - 1);
        float* sb = sums8 + ((size_t)slot * BATCH + b) * KDIM;
#pragma unroll
        for (int i = tid; i < KDIM; i += SEGTHR)
            unsafeAtomicAdd(sb + i, s_acc[i]);
    }
}

// ---------------------------------------------------------------------------
// Kernel 4: GEMM partials (unchanged proven kernel). 512 blocks (k-chunks
// of 32, 2/CU), 256 thr, each thread owns a float2 of j for all 4 batches.
// Means (8-slot sum / count) computed into LDS. 32 fully-unrolled
// nontemporal W loads in flight. Partials into 64 slots.
// ---------------------------------------------------------------------------
__global__ __launch_bounds__(256) void k_gemm_a(const float* __restrict__ Wm,
                                                const float* __restrict__ sums8,
                                                const int* __restrict__ counts,
                                                float* __restrict__ out_part) {
    __shared__ float s_m[4 * 32];   // [batch][kk]
    const int tid = threadIdx.x;
    const int kc  = blockIdx.x;     // 0..511
    const int k0  = kc * 32;
    if (tid < 128) {
        int bb = tid >> 5, kk = tid & 31, k = k0 + kk;
        float s = 0.f;
#pragma unroll
        for (int sl = 0; sl < SSLOTS; ++sl)
            s += sums8[(size_t)sl * BATCH * KDIM + (size_t)bb * KDIM + k];
        float cnt = (float)counts[k >> 8];
        s_m[tid] = s / fmaxf(cnt, 1.0f);
    }
    __syncthreads();

    const float* wp = Wm + (size_t)k0 * JDIM + 2 * tid;
    float2 a0 = {0.f, 0.f}, a1 = {0.f, 0.f}, a2 = {0.f, 0.f}, a3 = {0.f, 0.f};
#pragma unroll
    for (int kk = 0; kk < 32; ++kk) {
        float2 w = ntload2(wp + (size_t)kk * JDIM);
        float m0 = s_m[kk], m1 = s_m[32 + kk], m2 = s_m[64 + kk], m3 = s_m[96 + kk];
        a0.x += m0 * w.x; a0.y += m0 * w.y;
        a1.x += m1 * w.x; a1.y += m1 * w.y;
        a2.x += m2 * w.x; a2.y += m2 * w.y;
        a3.x += m3 * w.x; a3.y += m3 * w.y;
    }
    const int slot = kc & (GSLOTS - 1);
    float* op = out_part + (size_t)slot * 2048 + 2 * tid;
    unsafeAtomicAdd(op + 0,    a0.x); unsafeAtomicAdd(op + 1,    a0.y);
    unsafeAtomicAdd(op + 512,  a1.x); unsafeAtomicAdd(op + 513,  a1.y);
    unsafeAtomicAdd(op + 1024, a2.x); unsafeAtomicAdd(op + 1025, a2.y);
    unsafeAtomicAdd(op + 1536, a3.x); unsafeAtomicAdd(op + 1537, a3.y);
}

// Kernel 5: reduce 64 slots + bias -> out[4][512]. 512 KB read by 8 blocks.
__global__ __launch_bounds__(256) void k_gemm_b(const float* __restrict__ out_part,
                                                const float* __restrict__ bias,
                                                float* __restrict__ out) {
    const int idx = blockIdx.x * 256 + threadIdx.x;   // 0..2047
    const int j = idx & 511;
    float s = bias[j];
#pragma unroll
    for (int sl = 0; sl < GSLOTS; ++sl) s += out_part[(size_t)sl * 2048 + idx];
    out[idx] = s;
}

// ---------------------------------------------------------------------------
extern "C" void kernel_launch(void* const* d_in, const int* in_sizes, int n_in,
                              void* d_out, int out_size, void* d_ws, size_t ws_size,
                              hipStream_t stream) {
    const float* values = (const float*)d_in[0];  // [4, 65536, 256]
    const float* coords = (const float*)d_in[1];  // [65536, 2]
    const float* Wm     = (const float*)d_in[2];  // [16384, 512]
    const float* bias   = (const float*)d_in[3];  // [512]
    float* out = (float*)d_out;                   // [4, 512]

    char* ws = (char*)d_ws;
    // ws layout (bytes):
    int*   bins     = (int*)(ws + 0);            //  256 KB
    int*   hist_blk = (int*)(ws + 262144);       //   16 KB
    int*   counts   = (int*)(ws + 278528);       //  256 B
    float* sums8    = (float*)(ws + 278784);     //    2 MB  [8][4][16384]
    float* out_part = (float*)(ws + 2375936);    //  512 KB  [64][2048] (MUST follow sums8: zeroed as one range)

    k_bins  <<<64, 256, 0, stream>>>(coords, bins, hist_blk, (float4*)sums8);
    k_counts<<<1, 64, 0, stream>>>(hist_blk, counts);
    k_seg   <<<SEGGRID, SEGTHR, 0, stream>>>(values, bins, sums8);
    k_gemm_a<<<512, 256, 0, stream>>>(Wm, sums8, counts, out_part);
    k_gemm_b<<<8, 256, 0, stream>>>(out_part, bias, out);
}

// Round 4
// 393.390 us; speedup vs baseline: 1.7383x; 1.7332x over previous
//
#include <hip/hip_runtime.h>
#include <cstddef>

// Problem constants
#define NPTS   65536
#define BATCH  4
#define CH     256
#define HWBINS 64     // 8 x 8
#define KDIM   16384  // HWBINS * CH
#define JDIM   512
#define CHUNK  64     // rows per block in the big segment pass -> 1024 blocks
#define SSLOTS 8      // slot-spread copies of sums (atomic contention killer)
#define GSLOTS 64     // slot-spread copies of gemm partials
#define ZERO_F4 ((SSLOTS * BATCH * KDIM + GSLOTS * 2048) / 4)   // 163840 float4

// R1-R3 post-mortem (do NOT revisit): replacing the sort+register-accumulate
// k_seg with an LDS ds_add_f32 accumulator is ~200 cyc per LDS fp-atomic
// wave-instruction (measured invariant across safe/unsafe atomics, scalar/
// float4 loads, launch_bounds) -> 346-348 us vs ~45 us for this kernel.
// LDS fp atomics must never be on the per-element hot path.

// Native clang vector types — __builtin_nontemporal_load requires these
// (HIP_vector_type float4/float2 are structs and are rejected).
typedef float vf4 __attribute__((ext_vector_type(4)));
typedef float vf2 __attribute__((ext_vector_type(2)));

__device__ __forceinline__ float4 ntload4(const float* p) {
    vf4 v = __builtin_nontemporal_load((const vf4*)p);
    return make_float4(v.x, v.y, v.z, v.w);
}
__device__ __forceinline__ float2 ntload2(const float* p) {
    vf2 v = __builtin_nontemporal_load((const vf2*)p);
    return make_float2(v.x, v.y);
}

// ---------------------------------------------------------------------------
// Bucketization matching np.searchsorted(np.linspace(-1-eps, 1+eps, 9), x,
// 'right'). np.linspace is float64. (Verified: absmax 6e-5.)
// ---------------------------------------------------------------------------
__device__ __forceinline__ int bucket1d(float xf) {
    const double start = -1.0 - 1e-6;
    const double stop  =  1.0 + 1e-6;
    const double step  = (stop - start) / 8.0;
    double x = (double)xf;
    int k = 0;
#pragma unroll
    for (int i = 0; i < 8; ++i) k += ((double)i * step + start <= x) ? 1 : 0;
    k += (stop <= x) ? 1 : 0;
    int b = k - 1;
    return b < 0 ? 0 : (b > 7 ? 7 : b);
}

// Kernel 1: zero sums8+out_part (contiguous 2.5 MB) + per-point bin +
// per-block histogram. 64 blocks x 256 threads.
__global__ __launch_bounds__(256) void k_bins(const float* __restrict__ coords,
                                              int* __restrict__ bins,
                                              int* __restrict__ hist_blk,
                                              float4* __restrict__ zero4) {
    __shared__ int s_h[HWBINS];
    const int tid = threadIdx.x;
    const int blk = blockIdx.x;
    {
        const float4 z = make_float4(0.f, 0.f, 0.f, 0.f);
        for (int i = blk * 256 + tid; i < ZERO_F4; i += 64 * 256)
            zero4[i] = z;
    }
    if (tid < HWBINS) s_h[tid] = 0;
    __syncthreads();
#pragma unroll
    for (int i = 0; i < 4; ++i) {
        int n = blk * 1024 + i * 256 + tid;
        float2 xy = *(const float2*)(coords + 2 * (size_t)n);
        int bx = bucket1d(xy.x);
        int by = bucket1d(xy.y);
        int bin = by * 8 + bx;   // (kx-1) + (ky-1)*H, H=8
        bins[n] = bin;
        atomicAdd(&s_h[bin], 1);
    }
    __syncthreads();
    if (tid < HWBINS) hist_blk[blk * HWBINS + tid] = s_h[tid];
}

// Kernel 2: one wave. counts[bin], exclusive bin offsets, per-block bases.
__global__ void k_scan(const int* __restrict__ hist_blk,
                       int* __restrict__ counts,
                       int* __restrict__ block_base) {
    const int b = threadIdx.x;   // 0..63
    int tot = 0;
#pragma unroll 8
    for (int blk = 0; blk < 64; ++blk) tot += hist_blk[blk * HWBINS + b];
    counts[b] = tot;
    int inc = tot;
#pragma unroll
    for (int d = 1; d < 64; d <<= 1) {
        int v = __shfl_up(inc, d, 64);
        if (b >= d) inc += v;
    }
    int run = inc - tot;   // exclusive offset of this bin
#pragma unroll 8
    for (int blk = 0; blk < 64; ++blk) {
        int h = hist_blk[blk * HWBINS + b];
        block_base[blk * HWBINS + b] = run;
        run += h;
    }
}

// Kernel 3: scatter (row, bin) pairs into bin-sorted order.
__global__ __launch_bounds__(256) void k_scatter(const int* __restrict__ bins,
                                                 const int* __restrict__ block_base,
                                                 int2* __restrict__ pairs) {
    __shared__ int s_cur[HWBINS];
    const int tid = threadIdx.x;
    const int blk = blockIdx.x;
    if (tid < HWBINS) s_cur[tid] = block_base[blk * HWBINS + tid];
    __syncthreads();
#pragma unroll
    for (int i = 0; i < 4; ++i) {
        int n = blk * 1024 + i * 256 + tid;
        int bin = bins[n];
        int pos = atomicAdd(&s_cur[bin], 1);
        pairs[pos] = make_int2(n, bin);
    }
}

// ---------------------------------------------------------------------------
// Kernel 4: the 256 MB pass. 1024 blocks (4/CU, 16 waves/CU). Wave = one
// batch, 64 lanes x float4 = all 256 ch of a row. Rows bin-sorted ->
// register accumulate; flush via global f32 atomics only at bin boundaries
// (~17K total), spread over 8 sum slots. 8-deep nontemporal prefetch:
// 8 KB/wave, 128 KB/CU in flight vs ~9 KB needed at 6.3 TB/s.
// ---------------------------------------------------------------------------
__global__ __launch_bounds__(256) void k_seg(const float* __restrict__ values,
                                             const int2* __restrict__ pairs,
                                             float* __restrict__ sums8) {
    __shared__ int2 sp[CHUNK];
    const int tid = threadIdx.x;
    const int r0  = blockIdx.x * CHUNK;
    if (tid < CHUNK) sp[tid] = pairs[r0 + tid];
    __syncthreads();

    const int w    = tid >> 6;    // batch
    const int lane = tid & 63;    // channel group (float4)
    const int slot = blockIdx.x & (SSLOTS - 1);
    const float* vb = values + (size_t)w * NPTS * CH + lane * 4;
    float* sb = sums8 + (size_t)slot * BATCH * KDIM + (size_t)w * KDIM + lane * 4;

    float4 acc = make_float4(0.f, 0.f, 0.f, 0.f);
    int cur = sp[0].y;

    auto flushfn = [&](int nb) {
        float* d = sb + (size_t)cur * CH;
        unsafeAtomicAdd(d + 0, acc.x);
        unsafeAtomicAdd(d + 1, acc.y);
        unsafeAtomicAdd(d + 2, acc.z);
        unsafeAtomicAdd(d + 3, acc.w);
        acc = make_float4(0.f, 0.f, 0.f, 0.f);
        cur = nb;
    };

    float4 a[8], nx[8];
#pragma unroll
    for (int j = 0; j < 8; ++j)
        a[j] = ntload4(vb + (size_t)sp[j].x * CH);

#pragma unroll
    for (int g = 0; g < CHUNK; g += 8) {
        if (g + 8 < CHUNK) {           // issue next group's loads first
#pragma unroll
            for (int j = 0; j < 8; ++j)
                nx[j] = ntload4(vb + (size_t)sp[g + 8 + j].x * CH);
        }
#pragma unroll
        for (int j = 0; j < 8; ++j) {
            int bj = sp[g + j].y;
            if (bj != cur) flushfn(bj);    // wave-uniform, rare
            acc.x += a[j].x; acc.y += a[j].y; acc.z += a[j].z; acc.w += a[j].w;
        }
        if (g + 8 < CHUNK) {
#pragma unroll
            for (int j = 0; j < 8; ++j) a[j] = nx[j];
        }
    }
    flushfn(cur);   // final flush
}

// ---------------------------------------------------------------------------
// Kernel 5: GEMM partials. 512 blocks (k-chunks of 32, 2/CU, 8 waves/CU),
// 256 thr, each thread owns a float2 of j for all 4 batches. Means (8-slot
// sum / count) computed into LDS. 32 fully-unrolled nontemporal W loads in
// flight. Partials into 64 slots (8-way atomic contention).
// ---------------------------------------------------------------------------
__global__ __launch_bounds__(256) void k_gemm_a(const float* __restrict__ Wm,
                                                const float* __restrict__ sums8,
                                                const int* __restrict__ counts,
                                                float* __restrict__ out_part) {
    __shared__ float s_m[4 * 32];   // [batch][kk]
    const int tid = threadIdx.x;
    const int kc  = blockIdx.x;     // 0..511
    const int k0  = kc * 32;
    if (tid < 128) {
        int bb = tid >> 5, kk = tid & 31, k = k0 + kk;
        float s = 0.f;
#pragma unroll
        for (int sl = 0; sl < SSLOTS; ++sl)
            s += sums8[(size_t)sl * BATCH * KDIM + (size_t)bb * KDIM + k];
        float cnt = (float)counts[k >> 8];
        s_m[tid] = s / fmaxf(cnt, 1.0f);
    }
    __syncthreads();

    const float* wp = Wm + (size_t)k0 * JDIM + 2 * tid;
    float2 a0 = {0.f, 0.f}, a1 = {0.f, 0.f}, a2 = {0.f, 0.f}, a3 = {0.f, 0.f};
#pragma unroll
    for (int kk = 0; kk < 32; ++kk) {
        float2 w = ntload2(wp + (size_t)kk * JDIM);
        float m0 = s_m[kk], m1 = s_m[32 + kk], m2 = s_m[64 + kk], m3 = s_m[96 + kk];
        a0.x += m0 * w.x; a0.y += m0 * w.y;
        a1.x += m1 * w.x; a1.y += m1 * w.y;
        a2.x += m2 * w.x; a2.y += m2 * w.y;
        a3.x += m3 * w.x; a3.y += m3 * w.y;
    }
    const int slot = kc & (GSLOTS - 1);
    float* op = out_part + (size_t)slot * 2048 + 2 * tid;
    unsafeAtomicAdd(op + 0,    a0.x); unsafeAtomicAdd(op + 1,    a0.y);
    unsafeAtomicAdd(op + 512,  a1.x); unsafeAtomicAdd(op + 513,  a1.y);
    unsafeAtomicAdd(op + 1024, a2.x); unsafeAtomicAdd(op + 1025, a2.y);
    unsafeAtomicAdd(op + 1536, a3.x); unsafeAtomicAdd(op + 1537, a3.y);
}

// Kernel 6: reduce 64 slots + bias -> out[4][512]. 512 KB read by 8 blocks.
__global__ __launch_bounds__(256) void k_gemm_b(const float* __restrict__ out_part,
                                                const float* __restrict__ bias,
                                                float* __restrict__ out) {
    const int idx = blockIdx.x * 256 + threadIdx.x;   // 0..2047
    const int j = idx & 511;
    float s = bias[j];
#pragma unroll
    for (int sl = 0; sl < GSLOTS; ++sl) s += out_part[(size_t)sl * 2048 + idx];
    out[idx] = s;
}

// ---------------------------------------------------------------------------
extern "C" void kernel_launch(void* const* d_in, const int* in_sizes, int n_in,
                              void* d_out, int out_size, void* d_ws, size_t ws_size,
                              hipStream_t stream) {
    const float* values = (const float*)d_in[0];  // [4, 65536, 256]
    const float* coords = (const float*)d_in[1];  // [65536, 2]
    const float* Wm     = (const float*)d_in[2];  // [16384, 512]
    const float* bias   = (const float*)d_in[3];  // [512]
    float* out = (float*)d_out;                   // [4, 512]

    char* ws = (char*)d_ws;
    // ws layout (bytes):
    int*   bins       = (int*)(ws + 0);            //  256 KB
    int*   hist_blk   = (int*)(ws + 262144);       //   16 KB
    int*   counts     = (int*)(ws + 278528);       //  256 B
    int*   block_base = (int*)(ws + 278784);       //   16 KB
    int2*  pairs      = (int2*)(ws + 295168);      //  512 KB
    float* sums8      = (float*)(ws + 819456);     //    2 MB  [8][4][16384]
    float* out_part   = (float*)(ws + 2916608);    //  512 KB  [64][2048] (MUST follow sums8: zeroed as one range)

    k_bins   <<<64, 256, 0, stream>>>(coords, bins, hist_blk, (float4*)sums8);
    k_scan   <<<1, 64, 0, stream>>>(hist_blk, counts, block_base);
    k_scatter<<<64, 256, 0, stream>>>(bins, block_base, pairs);
    k_seg    <<<NPTS / CHUNK, 256, 0, stream>>>(values, pairs, sums8);
    k_gemm_a <<<512, 256, 0, stream>>>(Wm, sums8, counts, out_part);
    k_gemm_b <<<8, 256, 0, stream>>>(out_part, bias, out);
}